// Round 9
// baseline (144.070 us; speedup 1.0000x reference)
//
#include <hip/hip_runtime.h>
#include <math.h>

#define DD 160
#define HH 160
#define WW 160
#define NB 2
#define NEL (NB*DD*HH*WW)   // 8,192,000 voxels

#define XT 32               // x outputs per block
#define YT 16               // y outputs per block
#define ZC 10               // z outputs per block (R9: was 16; more blocks)
#define NTHR 256
#define NZCH (DD/ZC)        // 16
#define GX (WW/XT)          // 5
#define GY (HH/YT)          // 10
#define NBLK (GX*GY*NB*NZCH)   // 1600 blocks x 4 waves = 6400 waves (~25/CU)
#define NPART NBLK

#define HR 22               // halo rows (16 + 6)
#define NJOB (HR*8)         // 176 x-conv jobs (< NTHR)
#define CP 35               // c4 physical pitch in float4 (32 + swizzle)

typedef float v2f __attribute__((ext_vector_type(2)));

struct G7 { float g[7]; };

// Fully fused separable 3D SSIM, v8 = R8 + occupancy attack:
//  * ZC 16 -> 10: 1600 blocks (6.25/CU, 25 waves/CU = 78% ceiling vs 49%).
//    R8 evidence: HBM 9%, VALUBusy 50%, occupancy 34% -> stall-bound on
//    wave supply, and the +16% staging work is free (HBM/VALU headroom).
//  * induction-pointer prefetch (advance by slice stride, no per-slice
//    address recompute).
//  * frozen: XCD swizzle (FETCH 149->43MB), v2f pk-fma, c4 column swizzle,
//    dbuf + 1 barrier/slice, z register rings.
__global__ __launch_bounds__(NTHR, 4) void ssim_fused(
        const float* __restrict__ p, const float* __restrict__ t,
        float* __restrict__ partial, G7 gw) {
    const int tid = threadIdx.x;
    const int tx  = tid & 31;            // x output column (phase C)
    const int tyo = tid >> 5;            // 0..7, owns y = 2tyo, 2tyo+1

    // XCD-aware work remap (bijection on [0,NBLK))
    const int flat = blockIdx.x;
    const int w = (flat & 7) * (NBLK / 8) + (flat >> 3);
    const int bx = w % GX;
    const int by = (w / GX) % GY;
    const int bz = w / (GX * GY);        // 0..31

    const int x0 = bx * XT;
    const int y0 = by * YT;
    const int n  = bz / NZCH;
    const int zs = (bz % NZCH) * ZC;

    __shared__ float4 c4[2][HR][CP];

    // z rings: [y-out][slot], slot5 freshest
    v2f r01[2][6], r23[2][6];
#pragma unroll
    for (int yo = 0; yo < 2; ++yo)
#pragma unroll
        for (int j = 0; j < 6; ++j) {
            r01[yo][j] = (v2f)(0.f);
            r23[yo][j] = (v2f)(0.f);
        }

    const float C1v = 1e-4f, C2v = 9e-4f;
    float ssum = 0.f;
    const int hw = HH * WW;
    const float* pv = p + (size_t)n * DD * hw;
    const float* tv = t + (size_t)n * DD * hw;

    // phase-B job decode (tid < 176): row br, x-group bxg
    const int br = tid >> 3;             // 0..21
    const int bxg = tid & 7;             // 0..7
    const int bgy = y0 + br - 3;
    const bool browok = (unsigned)bgy < (unsigned)HH && tid < NJOB;
    const int cbase = x0 + 4 * bxg - 4;  // first loaded column (4-aligned)
    const int pcr = tx + (tx >> 3);      // C-phase swizzled column
    // per-q column validity (compile-time-unrollable predicates)
    bool qok[3];
#pragma unroll
    for (int q = 0; q < 3; ++q)
        qok[q] = browok && (unsigned)(cbase + 4 * q) < (unsigned)WW;

    // induction pointers: row bgy of slice currently being prefetched
    const float* prow = pv + (size_t)(zs - 3) * hw + bgy * WW;
    const float* trow = tv + (size_t)(zs - 3) * hw + bgy * WW;

    float4 pfa[3], pfb[3];
    auto prefetch = [&](int sx) {
#pragma unroll
        for (int q = 0; q < 3; ++q) {
            pfa[q] = make_float4(0.f, 0.f, 0.f, 0.f);
            pfb[q] = make_float4(0.f, 0.f, 0.f, 0.f);
        }
        if (sx >= 0 && sx < DD && sx < zs + ZC + 3) {
#pragma unroll
            for (int q = 0; q < 3; ++q) {
                if (qok[q]) {
                    pfa[q] = *(const float4*)(prow + cbase + 4 * q);
                    pfb[q] = *(const float4*)(trow + cbase + 4 * q);
                }
            }
        }
    };

    prefetch(zs - 3);

    for (int s = zs - 3; s < zs + ZC + 3; ++s) {
        const int par = s & 1;
        const bool valid = (s >= 0) && (s < DD);   // block-uniform

        if (valid) {
            // ---- B: x-conv from prefetched registers ----
            if (tid < NJOB) {
                v2f s01[4], s23[4];
#pragma unroll
                for (int e = 0; e < 4; ++e) { s01[e] = (v2f)(0.f); s23[e] = (v2f)(0.f); }
#pragma unroll
                for (int q = 0; q < 3; ++q) {
                    const float af[4] = {pfa[q].x, pfa[q].y, pfa[q].z, pfa[q].w};
                    const float bf[4] = {pfb[q].x, pfb[q].y, pfb[q].z, pfb[q].w};
#pragma unroll
                    for (int j = 0; j < 4; ++j) {
                        const int i = 4 * q + j;     // loaded position 0..11
                        v2f pt; pt[0] = af[j]; pt[1] = bf[j];
                        v2f ud; ud[0] = af[j] + bf[j]; ud[1] = af[j] - bf[j];
                        v2f qu = ud * ud;
#pragma unroll
                        for (int e = 0; e < 4; ++e) {
                            const int k = i - e - 1;  // tap index
                            if (k >= 0 && k < 7) {
                                s01[e] = gw.g[k] * pt + s01[e];
                                s23[e] = gw.g[k] * qu + s23[e];
                            }
                        }
                    }
                }
#pragma unroll
                for (int e = 0; e < 4; ++e) {
                    int c = 4 * bxg + e;
                    c4[par][br][c + (c >> 3)] =
                        make_float4(s01[e][0], s01[e][1], s23[e][0], s23[e][1]);
                }
            }
            __syncthreads();   // block-uniform (valid is uniform)
        }

        // ---- advance pointers, issue next slice's loads (overlap C) ----
        prow += hw; trow += hw;
        prefetch(s + 1);

        v2f m01[2], m23[2];
#pragma unroll
        for (int yo = 0; yo < 2; ++yo) {
            m01[yo] = (v2f)(0.f);
            m23[yo] = (v2f)(0.f);
        }

        if (valid) {
            // ---- C: y-conv, stream 8 rows for both y-outputs ----
#pragma unroll
            for (int r8 = 0; r8 < 8; ++r8) {
                float4 v = c4[par][2 * tyo + r8][pcr];
                v2f v01; v01[0] = v.x; v01[1] = v.y;
                v2f v23; v23[0] = v.z; v23[1] = v.w;
                if (r8 < 7) {
                    float w2 = gw.g[r8];
                    m01[0] = w2 * v01 + m01[0];
                    m23[0] = w2 * v23 + m23[0];
                }
                if (r8 > 0) {
                    float w2 = gw.g[r8 - 1];
                    m01[1] = w2 * v01 + m01[1];
                    m23[1] = w2 * v23 + m23[1];
                }
            }
            // no trailing barrier: dbuf; WAR fenced by next slice's barrier.
        }

        // ---- z rings: consume slot0, shift+FMA, refill ----
#pragma unroll
        for (int yo = 0; yo < 2; ++yo) {
            v2f v01 = m01[yo], v23 = m23[yo];
            v2f cons01 = gw.g[6] * v01 + r01[yo][0];
            v2f cons23 = gw.g[6] * v23 + r23[yo][0];
#pragma unroll
            for (int j = 0; j < 5; ++j) {
                r01[yo][j] = gw.g[5 - j] * v01 + r01[yo][j + 1];
                r23[yo][j] = gw.g[5 - j] * v23 + r23[yo][j + 1];
            }
            r01[yo][5] = gw.g[0] * v01;
            r23[yo][5] = gw.g[0] * v23;

            if (s >= zs + 3) {   // output z = s-3
                float mu1 = cons01[0], mu2 = cons01[1];
                float Eu  = cons23[0], Ew  = cons23[1];
                float mu12 = mu1 * mu2, mu1sq = mu1 * mu1, mu2sq = mu2 * mu2;
                float sumsq = 0.5f  * (Eu + Ew) - mu1sq - mu2sq; // s1+s2
                float s12   = 0.25f * (Eu - Ew) - mu12;          // sigma12
                float num = (2.f * mu12 + C1v) * (2.f * s12 + C2v);
                float den = (mu1sq + mu2sq + C1v) * (sumsq + C2v);
                ssum += num * __builtin_amdgcn_rcpf(den);
            }
        }
    }

    // ---- block reduction (4 waves) ----
#pragma unroll
    for (int off = 32; off > 0; off >>= 1)
        ssum += __shfl_down(ssum, off, 64);
    __shared__ float wsum[4];
    if ((tid & 63) == 0) wsum[tid >> 6] = ssum;
    __syncthreads();
    if (tid == 0)
        partial[flat] = wsum[0] + wsum[1] + wsum[2] + wsum[3];
}

__global__ __launch_bounds__(256) void ssim_final(
        const float* __restrict__ partial, float* __restrict__ out) {
    float s = 0.f;
    for (int i = threadIdx.x; i < NPART; i += 256) s += partial[i];
#pragma unroll
    for (int off = 32; off > 0; off >>= 1)
        s += __shfl_down(s, off, 64);
    __shared__ float wsum[4];
    int lane = threadIdx.x & 63, wid = threadIdx.x >> 6;
    if (lane == 0) wsum[wid] = s;
    __syncthreads();
    if (threadIdx.x == 0) {
        float tot = wsum[0] + wsum[1] + wsum[2] + wsum[3];
        out[0] = 1.0f - tot / (float)NEL;
    }
}

extern "C" void kernel_launch(void* const* d_in, const int* in_sizes, int n_in,
                              void* d_out, int out_size, void* d_ws, size_t ws_size,
                              hipStream_t stream) {
    const float* p = (const float*)d_in[0];
    const float* t = (const float*)d_in[1];
    float* out = (float*)d_out;
    float* partial = (float*)d_ws;   // NPART floats

    G7 gw;
    {
        double s = 0.0, sig = 7.0 / 6.0;
        double g[7];
        for (int i = 0; i < 7; ++i) {
            double d = (double)i - 3.0;
            g[i] = exp(-d * d / (2.0 * sig * sig));
            s += g[i];
        }
        for (int i = 0; i < 7; ++i) gw.g[i] = (float)(g[i] / s);
    }

    ssim_fused<<<NBLK, NTHR, 0, stream>>>(p, t, partial, gw);
    ssim_final<<<1, 256, 0, stream>>>(partial, out);
}

// Round 10
// 134.873 us; speedup vs baseline: 1.0682x; 1.0682x over previous
//
#include <hip/hip_runtime.h>
#include <math.h>

#define DD 160
#define HH 160
#define WW 160
#define NB 2
#define NEL (NB*DD*HH*WW)   // 8,192,000 voxels

#define XT 32               // x outputs per block
#define YT 16               // y outputs per block
#define ZC 16               // z outputs per block (reverted: R9 showed more
                            // blocks don't raise residency, only add work)
#define NTHR 256
#define NZCH (DD/ZC)        // 10
#define GX (WW/XT)          // 5
#define GY (HH/YT)          // 10
#define NBLK (GX*GY*NB*NZCH)   // 1000 blocks x 4 waves
#define NPART NBLK

#define HR 22               // halo rows (16 + 6)
#define NJOB (HR*8)         // 176 x-conv jobs
#define NJOBW 44            // jobs per wave (4 x 44 = 176, wave-balanced)
#define CP 35               // c4 physical pitch in float4 (32 + swizzle)

typedef float v2f __attribute__((ext_vector_type(2)));

struct G7 { float g[7]; };

// Fully fused separable 3D SSIM, v9 = R8 + skewed pipeline:
//  * R8 evidence: VALU 29.5us + LDS 18.5us + conflicts 4.5us ~= 52.5 of 59us
//    -> pipes serialized by the B->barrier->C phase structure (co-resident
//    blocks run in lockstep, so phases align chip-wide).
//  * Skewed loop: barrier; B(s+1)->c4[(s+1)&1]; prefetch(s+2); C(s) from
//    c4[s&1]; ring(s). B-writes and C-reads hit different parities -> no
//    intra-iteration dependency -> VALU and LDS pipes overlap per-wave.
//  * Wave-balanced B jobs (44/wave): all 4 SIMDs issue during B (was 2.75).
//  * Uniform zero-padding via prefetch: no divergent valid branches.
//  * Frozen: XCD swizzle (FETCH 149->43MB), v2f pk-fma, c4 column swizzle,
//    z register rings, in-register SSIM + block reduce.
__global__ __launch_bounds__(NTHR, 4) void ssim_fused(
        const float* __restrict__ p, const float* __restrict__ t,
        float* __restrict__ partial, G7 gw) {
    const int tid = threadIdx.x;
    const int tx  = tid & 31;            // x output column (phase C)
    const int tyo = tid >> 5;            // 0..7, owns y = 2tyo, 2tyo+1

    // XCD-aware work remap (bijection on [0,NBLK))
    const int flat = blockIdx.x;
    const int w = (flat & 7) * (NBLK / 8) + (flat >> 3);
    const int bx = w % GX;
    const int by = (w / GX) % GY;
    const int bz = w / (GX * GY);

    const int x0 = bx * XT;
    const int y0 = by * YT;
    const int n  = bz / NZCH;
    const int zs = (bz % NZCH) * ZC;
    const int send = zs + ZC + 3;        // one past last staged slice

    __shared__ float4 c4[2][HR][CP];

    // z rings: [y-out][slot], slot5 freshest
    v2f r01[2][6], r23[2][6];
#pragma unroll
    for (int yo = 0; yo < 2; ++yo)
#pragma unroll
        for (int j = 0; j < 6; ++j) {
            r01[yo][j] = (v2f)(0.f);
            r23[yo][j] = (v2f)(0.f);
        }

    const float C1v = 1e-4f, C2v = 9e-4f;
    float ssum = 0.f;
    const int hw = HH * WW;
    const float* pv = p + (size_t)n * DD * hw;
    const float* tv = t + (size_t)n * DD * hw;

    // ---- wave-balanced B-job decode ----
    const int lane = tid & 63, wv = tid >> 6;
    const int j = wv * NJOBW + lane;     // 0..175 when lane < 44
    const bool jok = lane < NJOBW;
    const int br  = j >> 3;              // row 0..21
    const int bxg = j & 7;               // x-group 0..7
    const int bgy = y0 + br - 3;
    const bool browok = jok && (unsigned)bgy < (unsigned)HH;
    const int cbase = x0 + 4 * bxg - 4;  // first loaded column (4-aligned)
    const int pcr = tx + (tx >> 3);      // C-phase swizzled column
    bool qok[3];
#pragma unroll
    for (int q = 0; q < 3; ++q)
        qok[q] = browok && (unsigned)(cbase + 4 * q) < (unsigned)WW;

    // induction pointers for the slice currently being prefetched
    const float* prow = pv + (size_t)(zs - 3) * hw + bgy * WW;
    const float* trow = tv + (size_t)(zs - 3) * hw + bgy * WW;

    float4 pfa[3], pfb[3];
    auto prefetch = [&](int sx) {
#pragma unroll
        for (int q = 0; q < 3; ++q) {
            pfa[q] = make_float4(0.f, 0.f, 0.f, 0.f);
            pfb[q] = make_float4(0.f, 0.f, 0.f, 0.f);
        }
        if (sx >= 0 && sx < DD && sx < send) {
#pragma unroll
            for (int q = 0; q < 3; ++q) {
                if (qok[q]) {
                    pfa[q] = *(const float4*)(prow + cbase + 4 * q);
                    pfb[q] = *(const float4*)(trow + cbase + 4 * q);
                }
            }
        }
    };

    // x-conv of the prefetched slice -> c4[par]  (zeros when pf is zeros)
    auto do_B = [&](int par) {
        if (jok) {
            v2f s01[4], s23[4];
#pragma unroll
            for (int e = 0; e < 4; ++e) { s01[e] = (v2f)(0.f); s23[e] = (v2f)(0.f); }
#pragma unroll
            for (int q = 0; q < 3; ++q) {
                const float af[4] = {pfa[q].x, pfa[q].y, pfa[q].z, pfa[q].w};
                const float bf[4] = {pfb[q].x, pfb[q].y, pfb[q].z, pfb[q].w};
#pragma unroll
                for (int jj = 0; jj < 4; ++jj) {
                    const int i = 4 * q + jj;      // loaded position 0..11
                    v2f pt; pt[0] = af[jj]; pt[1] = bf[jj];
                    v2f ud; ud[0] = af[jj] + bf[jj]; ud[1] = af[jj] - bf[jj];
                    v2f qu = ud * ud;
#pragma unroll
                    for (int e = 0; e < 4; ++e) {
                        const int k = i - e - 1;   // tap index
                        if (k >= 0 && k < 7) {
                            s01[e] = gw.g[k] * pt + s01[e];
                            s23[e] = gw.g[k] * qu + s23[e];
                        }
                    }
                }
            }
#pragma unroll
            for (int e = 0; e < 4; ++e) {
                int c = 4 * bxg + e;
                c4[par][br][c + (c >> 3)] =
                    make_float4(s01[e][0], s01[e][1], s23[e][0], s23[e][1]);
            }
        }
    };

    // ---- prologue: stage slice zs-3, prefetch zs-2 ----
    prefetch(zs - 3);
    do_B((zs - 3) & 1);
    prow += hw; trow += hw;
    prefetch(zs - 2);

    for (int s = zs - 3; s < send; ++s) {
        __syncthreads();   // fences prev iter's B-writes before C(s) reads;
                           // also fences C(s-1) reads before this B's writes.

        // ---- B(s+1): x-conv into the other parity (no dep on C(s)) ----
        if (s + 1 < send) do_B((s + 1) & 1);

        // ---- issue prefetch of slice s+2 ----
        prow += hw; trow += hw;
        prefetch(s + 2);

        // ---- C(s): y-conv from c4[s&1] ----
        v2f m01[2], m23[2];
#pragma unroll
        for (int yo = 0; yo < 2; ++yo) {
            m01[yo] = (v2f)(0.f);
            m23[yo] = (v2f)(0.f);
        }
#pragma unroll
        for (int r8 = 0; r8 < 8; ++r8) {
            float4 v = c4[s & 1][2 * tyo + r8][pcr];
            v2f v01; v01[0] = v.x; v01[1] = v.y;
            v2f v23; v23[0] = v.z; v23[1] = v.w;
            if (r8 < 7) {
                float w2 = gw.g[r8];
                m01[0] = w2 * v01 + m01[0];
                m23[0] = w2 * v23 + m23[0];
            }
            if (r8 > 0) {
                float w2 = gw.g[r8 - 1];
                m01[1] = w2 * v01 + m01[1];
                m23[1] = w2 * v23 + m23[1];
            }
        }

        // ---- z rings: consume slot0, shift+FMA, refill ----
#pragma unroll
        for (int yo = 0; yo < 2; ++yo) {
            v2f v01 = m01[yo], v23 = m23[yo];
            v2f cons01 = gw.g[6] * v01 + r01[yo][0];
            v2f cons23 = gw.g[6] * v23 + r23[yo][0];
#pragma unroll
            for (int jj = 0; jj < 5; ++jj) {
                r01[yo][jj] = gw.g[5 - jj] * v01 + r01[yo][jj + 1];
                r23[yo][jj] = gw.g[5 - jj] * v23 + r23[yo][jj + 1];
            }
            r01[yo][5] = gw.g[0] * v01;
            r23[yo][5] = gw.g[0] * v23;

            if (s >= zs + 3) {   // output z = s-3
                float mu1 = cons01[0], mu2 = cons01[1];
                float Eu  = cons23[0], Ew  = cons23[1];
                float mu12 = mu1 * mu2, mu1sq = mu1 * mu1, mu2sq = mu2 * mu2;
                float sumsq = 0.5f  * (Eu + Ew) - mu1sq - mu2sq; // s1+s2
                float s12   = 0.25f * (Eu - Ew) - mu12;          // sigma12
                float num = (2.f * mu12 + C1v) * (2.f * s12 + C2v);
                float den = (mu1sq + mu2sq + C1v) * (sumsq + C2v);
                ssum += num * __builtin_amdgcn_rcpf(den);
            }
        }
    }

    // ---- block reduction (4 waves) ----
#pragma unroll
    for (int off = 32; off > 0; off >>= 1)
        ssum += __shfl_down(ssum, off, 64);
    __shared__ float wsum[4];
    if ((tid & 63) == 0) wsum[tid >> 6] = ssum;
    __syncthreads();
    if (tid == 0)
        partial[flat] = wsum[0] + wsum[1] + wsum[2] + wsum[3];
}

__global__ __launch_bounds__(256) void ssim_final(
        const float* __restrict__ partial, float* __restrict__ out) {
    float s = 0.f;
    for (int i = threadIdx.x; i < NPART; i += 256) s += partial[i];
#pragma unroll
    for (int off = 32; off > 0; off >>= 1)
        s += __shfl_down(s, off, 64);
    __shared__ float wsum[4];
    int lane = threadIdx.x & 63, wid = threadIdx.x >> 6;
    if (lane == 0) wsum[wid] = s;
    __syncthreads();
    if (threadIdx.x == 0) {
        float tot = wsum[0] + wsum[1] + wsum[2] + wsum[3];
        out[0] = 1.0f - tot / (float)NEL;
    }
}

extern "C" void kernel_launch(void* const* d_in, const int* in_sizes, int n_in,
                              void* d_out, int out_size, void* d_ws, size_t ws_size,
                              hipStream_t stream) {
    const float* p = (const float*)d_in[0];
    const float* t = (const float*)d_in[1];
    float* out = (float*)d_out;
    float* partial = (float*)d_ws;   // NPART floats

    G7 gw;
    {
        double s = 0.0, sig = 7.0 / 6.0;
        double g[7];
        for (int i = 0; i < 7; ++i) {
            double d = (double)i - 3.0;
            g[i] = exp(-d * d / (2.0 * sig * sig));
            s += g[i];
        }
        for (int i = 0; i < 7; ++i) gw.g[i] = (float)(g[i] / s);
    }

    ssim_fused<<<NBLK, NTHR, 0, stream>>>(p, t, partial, gw);
    ssim_final<<<1, 256, 0, stream>>>(partial, out);
}